// Round 10
// baseline (113.148 us; speedup 1.0000x reference)
//
#include <hip/hip_runtime.h>
#include <math.h>

#define NQ   10
#define NLAY 4
#define BATCH 4096
#define HID  32
#define NM   20   // 2*NQ

typedef float    f2  __attribute__((ext_vector_type(2)));
typedef unsigned u2v __attribute__((ext_vector_type(2)));

// ---------------------------------------------------------------------------
// Compile-time tracking of the CNOT ring as a GF(2) linear map.
// col[l][k] = pair-xor mask between storage indices for layer-l gate on wire k
// row[l][k] = parity mask giving logical bit x_k from storage index
// Storage bit layout THIS kernel: s = (lane<<4) | (r<<1) | wavebit
//   bits 9..4 -> lane (6b), bits 3..1 -> reg r (3b), bit 0 -> wave of pair
// ---------------------------------------------------------------------------
struct Tables {
    unsigned col[NLAY + 1][NQ];
    unsigned row[NLAY + 1][NQ];
};

constexpr Tables make_tables() {
    Tables t{};
    unsigned col[NQ] = {}, row[NQ] = {};
    for (int k = 0; k < NQ; ++k) { col[k] = 1u << (NQ - 1 - k); row[k] = 1u << (NQ - 1 - k); }
    for (int l = 0; l <= NLAY; ++l) {
        for (int k = 0; k < NQ; ++k) { t.col[l][k] = col[k]; t.row[l][k] = row[k]; }
        for (int k = 0; k < NQ; ++k) {            // ring: CNOT(k, (k+1)%NQ)
            int c = k, tg = (k + 1) % NQ;
            col[c] ^= col[tg];
            row[tg] ^= row[c];
        }
    }
    return t;
}

static constexpr Tables TB = make_tables();

struct cpx { float x, y; };
__device__ __forceinline__ cpx cxmul(cpx a, cpx b) {
    return { fmaf(a.x, b.x, -a.y * b.y), fmaf(a.x, b.y, a.y * b.x) };
}

__device__ __forceinline__ f2 mk2(float a, float b) { f2 r; r[0] = a; r[1] = b; return r; }
__device__ __forceinline__ f2 ffma(f2 a, f2 b, f2 c) { return __builtin_elementwise_fma(a, b, c); }

// acc += a (*) b   complex, interleaved (re,im) per f2 (VOP3P-foldable shapes).
__device__ __forceinline__ f2 cmac(f2 acc, f2 a, f2 b) {
    acc = ffma(mk2(a[0], a[0]), b, acc);
    acc = ffma(mk2(-a[1], a[1]), mk2(b[1], b[0]), acc);
    return acc;
}

// ---- DPP lane-xor within a 16-lane row (VALU pipe) ------------------------
template<int CTRL>
__device__ __forceinline__ float dppf(float x) {
    return __int_as_float(__builtin_amdgcn_update_dpp(
        0, __float_as_int(x), CTRL, 0xF, 0xF, true));
}

template<unsigned M>
__device__ __forceinline__ float dpplo(float x) {
    static_assert(M < 16u, "dpplo handles masks 0..15");
    if constexpr (M == 0u)       return x;
    else if constexpr (M == 1u)  return dppf<0xB1>(x);                 // quad_perm [1,0,3,2]
    else if constexpr (M == 2u)  return dppf<0x4E>(x);                 // quad_perm [2,3,0,1]
    else if constexpr (M == 3u)  return dppf<0x1B>(x);                 // quad_perm [3,2,1,0]
    else if constexpr (M == 7u)  return dppf<0x141>(x);                // row_half_mirror
    else if constexpr (M == 8u)  return dppf<0x128>(x);                // row_ror:8
    else if constexpr (M == 15u) return dppf<0x140>(x);                // row_mirror
    else if constexpr (M == 4u)  return dppf<0x141>(dppf<0x1B>(x));    // 7^3
    else if constexpr (M == 5u)  return dppf<0x141>(dppf<0x4E>(x));    // 7^2
    else if constexpr (M == 6u)  return dppf<0x141>(dppf<0xB1>(x));    // 7^1
    else if constexpr (M == 9u)  return dppf<0x128>(dppf<0xB1>(x));    // 8^1
    else if constexpr (M == 10u) return dppf<0x128>(dppf<0x4E>(x));    // 8^2
    else if constexpr (M == 11u) return dppf<0x128>(dppf<0x1B>(x));    // 8^3
    else if constexpr (M == 12u) return dppf<0x140>(dppf<0x1B>(x));    // 15^3
    else if constexpr (M == 13u) return dppf<0x140>(dppf<0x4E>(x));    // 15^2
    else                         return dppf<0x140>(dppf<0xB1>(x));    // 14 = 15^1
}

// ---- gfx950 permlane row swaps (VALU pipe); sel probed at runtime ---------
__device__ __forceinline__ float swap16sel(float x, bool sel16) {
#if __has_builtin(__builtin_amdgcn_permlane16_swap)
    u2v r = __builtin_amdgcn_permlane16_swap(__float_as_uint(x), __float_as_uint(x), false, false);
    return sel16 ? __uint_as_float(r[0]) : __uint_as_float(r[1]);
#else
    (void)sel16; return __shfl_xor(x, 16);
#endif
}
__device__ __forceinline__ float swap32sel(float x, bool sel32) {
#if __has_builtin(__builtin_amdgcn_permlane32_swap)
    u2v r = __builtin_amdgcn_permlane32_swap(__float_as_uint(x), __float_as_uint(x), false, false);
    return sel32 ? __uint_as_float(r[0]) : __uint_as_float(r[1]);
#else
    (void)sel32; return __shfl_xor(x, 32);
#endif
}
__device__ __forceinline__ float redfold16(float x) {
#if __has_builtin(__builtin_amdgcn_permlane16_swap)
    u2v r = __builtin_amdgcn_permlane16_swap(__float_as_uint(x), __float_as_uint(x), false, false);
    return __uint_as_float(r[0]) + __uint_as_float(r[1]);
#else
    return x + __shfl_xor(x, 16);
#endif
}
__device__ __forceinline__ float redfold32(float x) {
#if __has_builtin(__builtin_amdgcn_permlane32_swap)
    u2v r = __builtin_amdgcn_permlane32_swap(__float_as_uint(x), __float_as_uint(x), false, false);
    return __uint_as_float(r[0]) + __uint_as_float(r[1]);
#else
    return x + __shfl_xor(x, 32);
#endif
}

// lane-xor by compile-time MASK, all on the VALU pipe (gate loop has no DS
// swizzles; cross-wave gates use the LDS exchange instead).
template<unsigned M>
__device__ __forceinline__ float xlane(float x, bool sel16, bool sel32) {
    float y = dpplo<M & 15u>(x);
    if constexpr ((M & 16u) != 0u) y = swap16sel(y, sel16);
    if constexpr ((M & 32u) != 0u) y = swap32sel(y, sel32);
    return y;
}

#define XSTRIDE 18   // floats per lane slot in xbuf (72 B: 8-B aligned, low conflict)

// ---- one single-qubit gate, 2-wave split state, fully specialized ---------
template<int L, int K>
__device__ __forceinline__ void apply_gate(f2 (&st)[8], const float4 (*gm)[2],
                                           float* xbuf, const int lane, const int wv,
                                           const bool sel16, const bool sel32) {
    constexpr unsigned v     = TB.col[L][K];
    constexpr unsigned m     = TB.row[L][K];
    constexpr unsigned vlane = (v >> 4) & 63u;
    constexpr int      vr    = (int)((v >> 1) & 7u);
    constexpr int      vw    = (int)(v & 1u);
    constexpr unsigned mlane = (m >> 4) & 63u;
    constexpr int      mr    = (int)((m >> 1) & 7u);
    constexpr int      mw    = (int)(m & 1u);
    constexpr int      gi    = L * NQ + K;

    int laneP = 0;
    if constexpr (mlane != 0u || mw != 0)
        laneP = (__popc((unsigned)lane & mlane) ^ (wv & mw)) & 1;
    const float4 A = gm[gi][laneP];
    const f2 ocA = mk2(A.x, A.y), pcA = mk2(A.z, A.w);
    f2 ocB = ocA, pcB = pcA;
    if constexpr (mr != 0) {
        const float4 B = gm[gi][laneP ^ 1];
        ocB = mk2(B.x, B.y); pcB = mk2(B.z, B.w);
    }

    f2 pv[8];
    if constexpr (vw != 0) {
        // cross-wave: exchange full state through LDS; the read address also
        // absorbs the lane-xor and reg-xor parts of the pair mask.
        float* slot = xbuf + (unsigned)(wv * 64 + lane) * XSTRIDE;
        #pragma unroll
        for (int r = 0; r < 8; ++r) *(f2*)(slot + 2 * r) = st[r];
        __syncthreads();
        const float* ps = xbuf + (unsigned)((wv ^ 1) * 64 + (lane ^ (int)vlane)) * XSTRIDE;
        #pragma unroll
        for (int r = 0; r < 8; ++r) pv[r] = *(const f2*)(ps + 2 * (r ^ vr));
        __syncthreads();   // WAR: xbuf reused by the next exchange
    } else if constexpr (vlane != 0u) {
        #pragma unroll
        for (int r = 0; r < 8; ++r) {
            const f2 q = st[r ^ vr];
            pv[r] = mk2(xlane<vlane>(q[0], sel16, sel32),
                        xlane<vlane>(q[1], sel16, sel32));
        }
    } else {
        #pragma unroll
        for (int r = 0; r < 8; ++r) pv[r] = st[r ^ vr];
    }

    #pragma unroll
    for (int r = 0; r < 8; ++r) {
        const int pr = __builtin_popcount((unsigned)(r & mr)) & 1;  // compile-time
        const f2 oc = pr ? ocB : ocA;
        const f2 pc = pr ? pcB : pcA;
        f2 acc = mk2(0.f, 0.f);
        acc = cmac(acc, oc, st[r]);
        acc = cmac(acc, pc, pv[r]);
        st[r] = acc;
    }
}

// One block = one batch element = 2 waves (128 threads); 8 amps (f2) per lane.
__global__ __launch_bounds__(128)
__attribute__((amdgpu_waves_per_eu(7)))
void qrh_kernel(
    const float* __restrict__ theta, const float* __restrict__ rotw,
    const float* __restrict__ escale, const float* __restrict__ ebias,
    const float* __restrict__ W1, const float* __restrict__ b1,
    const float* __restrict__ W2, const float* __restrict__ b2,
    float* __restrict__ out)
{
    __shared__ float4 gmat[NLAY * NQ][2];   // [gate][U00,U01 | U11,U10]
    __shared__ float4 wtab[NQ];             // layer-0 product vectors
    __shared__ float  xbuf[2 * 64 * XSTRIDE];
    __shared__ float  fbuf[NM];

    const int tid  = threadIdx.x;
    const int lane = tid & 63;
    const int wv   = tid >> 6;     // wave of the pair = storage bit 0
    const int b    = blockIdx.x;

    // probe permlane swap convention once: sel ? r[0] : r[1]  ==  x[lane^16/32]
    bool sel16 = false, sel32 = false;
#if __has_builtin(__builtin_amdgcn_permlane16_swap)
    {
        u2v r = __builtin_amdgcn_permlane16_swap((unsigned)lane, (unsigned)lane, false, false);
        sel16 = (r[0] == (unsigned)(lane ^ 16));
    }
#endif
#if __has_builtin(__builtin_amdgcn_permlane32_swap)
    {
        u2v r = __builtin_amdgcn_permlane32_swap((unsigned)lane, (unsigned)lane, false, false);
        sel32 = (r[0] == (unsigned)(lane ^ 32));
    }
#endif

    // ---- per-gate 2x2 unitary, lane-parallel (threads 0..39) ----
    if (tid < NLAY * NQ) {
        const int g = tid, l = g / NQ, k = g % NQ;
        const float th = theta[b * NQ + k];
        const int e2 = (l * NQ + k) * 2;
        const float t0 = escale[e2 + 0] * th + ebias[e2 + 0];
        const float t1 = escale[e2 + 1] * th + ebias[e2 + 1];
        float sn0, c0, sn1, c1;
        __sincosf(0.5f * t0, &sn0, &c0);
        __sincosf(0.5f * t1, &sn1, &c1);
        // U_enc = RX(t1) RZ(t0)
        const f2 E00 = mk2( c1 * c0,  -c1 * sn0);
        const f2 E01 = mk2( sn1 * sn0, -sn1 * c0);
        const f2 E10 = mk2(-sn1 * sn0, -sn1 * c0);
        const f2 E11 = mk2( c1 * c0,   c1 * sn0);
        const int r3 = (l * NQ + k) * 3;
        const float w0 = rotw[r3 + 0], w1 = rotw[r3 + 1], w2 = rotw[r3 + 2];
        float cw, sw, ca0, sa0, ca1, sa1;
        __sincosf(0.5f * w1, &sw, &cw);
        __sincosf(0.5f * (w0 + w2), &sa0, &ca0);
        __sincosf(0.5f * (w0 - w2), &sa1, &ca1);
        // U_rot = RZ(w2) RY(w1) RZ(w0)
        const f2 R00 = mk2( cw * ca0, -cw * sa0);
        const f2 R01 = mk2(-sw * ca1, -sw * sa1);
        const f2 R10 = mk2( sw * ca1, -sw * sa1);
        const f2 R11 = mk2( cw * ca0,  cw * sa0);
        auto cm = [](f2 a, f2 bb) { return mk2(a[0]*bb[0] - a[1]*bb[1], a[0]*bb[1] + a[1]*bb[0]); };
        const f2 U00 = cm(R00, E00) + cm(R01, E10);
        const f2 U01 = cm(R00, E01) + cm(R01, E11);
        const f2 U10 = cm(R10, E00) + cm(R11, E10);
        const f2 U11 = cm(R10, E01) + cm(R11, E11);
        gmat[g][0] = make_float4(U00[0], U00[1], U01[0], U01[1]);
        gmat[g][1] = make_float4(U11[0], U11[1], U10[0], U10[1]);
        if (l == 0) {
            // layer-0 acts on |+>^10: per-wire 2-vector w = U*(1,1)/sqrt(2)
            const float inv = 0.70710678118654752f;
            const f2 al = (U00 + U01) * inv;
            const f2 be = (U10 + U11) * inv;
            wtab[k] = make_float4(al[0], al[1], be[0], be[1]);
        }
    }
    __syncthreads();

    // ---- layer-0 state = product state: amp(s) = prod_k w_k[s_k] ----------
    // s = (lane<<4)|(r<<1)|wv ; wires 0..5 <-> lane bits 5..0;
    // wires 6,7,8 <-> r bits 2..0; wire 9 <-> wv
    f2 st[8];
    {
        cpx pre;
        {
            const float4 q = wtab[0];
            pre = ((lane >> 5) & 1) ? cpx{q.z, q.w} : cpx{q.x, q.y};
            #pragma unroll
            for (int k = 1; k < 6; ++k) {
                const float4 t = wtab[k];
                const cpx w_ = ((lane >> (5 - k)) & 1) ? cpx{t.z, t.w} : cpx{t.x, t.y};
                pre = cxmul(pre, w_);
            }
            const float4 q9 = wtab[9];
            const cpx w9v = wv ? cpx{q9.z, q9.w} : cpx{q9.x, q9.y};
            pre = cxmul(pre, w9v);
        }
        const float4 q6 = wtab[6], q7 = wtab[7], q8 = wtab[8];
        const cpx w6[2] = {{q6.x, q6.y}, {q6.z, q6.w}};
        const cpx w7[2] = {{q7.x, q7.y}, {q7.z, q7.w}};
        const cpx w8[2] = {{q8.x, q8.y}, {q8.z, q8.w}};
        cpx ph[4];
        #pragma unroll
        for (int a = 0; a < 4; ++a) ph[a] = cxmul(cxmul(pre, w6[a >> 1]), w7[a & 1]);
        #pragma unroll
        for (int r = 0; r < 8; ++r) {
            const cpx t = cxmul(ph[r >> 1], w8[r & 1]);
            st[r] = mk2(t.x, t.y);
        }
    }

    const float4 (*gm)[2] = gmat;

    #define GATE(L,K) apply_gate<L,K>(st, gm, xbuf, lane, wv, sel16, sel32);
    #define LAYER(L) GATE(L,0) GATE(L,1) GATE(L,2) GATE(L,3) GATE(L,4) \
                     GATE(L,5) GATE(L,6) GATE(L,7) GATE(L,8) GATE(L,9)
    LAYER(1)
    LAYER(2)
    LAYER(3)
    #undef LAYER
    #undef GATE

    // ---- measurement: probs then 3-bit FWHT over register index ----
    float w[8];
    #pragma unroll
    for (int r = 0; r < 8; ++r) {
        const f2 sq = st[r] * st[r];
        w[r] = sq[0] + sq[1];
    }
    #pragma unroll
    for (int bit = 1; bit < 8; bit <<= 1) {
        #pragma unroll
        for (int j = 0; j < 8; ++j) {
            if (!(j & bit)) {
                const float a = w[j], c = w[j | bit];
                w[j] = a + c; w[j | bit] = a - c;
            }
        }
    }
    // w[t] = sum_r (-1)^{popc(r&t)} p[r]

    float feats[NM];
    #pragma unroll
    for (int f = 0; f < NM; ++f) {
        const unsigned M = (f < NQ) ? TB.row[NLAY][f]
                                    : (TB.row[NLAY][f - NQ] ^ TB.row[NLAY][(f - NQ + 1) % NQ]);
        const unsigned Mlane = (M >> 4) & 63u;
        const int Mr = (int)((M >> 1) & 7u);
        const int Mw = (int)(M & 1u);
        const float s = w[Mr];
        const int lsgn = (__popc((unsigned)lane & Mlane) ^ (wv & Mw)) & 1;
        feats[f] = lsgn ? -s : s;
    }
    // wave reduction over basis masks {1,2,7,8,16,32} (all VALU)
    #pragma unroll
    for (int f = 0; f < NM; ++f) {
        float v = feats[f];
        v += dppf<0xB1>(v);    // ^1
        v += dppf<0x4E>(v);    // ^2
        v += dppf<0x141>(v);   // ^7
        v += dppf<0x128>(v);   // ^8
        v = redfold16(v);
        v = redfold32(v);
        feats[f] = v;
    }

    // ---- cross-wave feat reduction + MLP head on wave 0 ----
    if (wv == 1 && lane == 0) {
        #pragma unroll
        for (int f = 0; f < NM; ++f) fbuf[f] = feats[f];
    }
    __syncthreads();
    if (wv == 0) {
        #pragma unroll
        for (int f = 0; f < NM; ++f) feats[f] += fbuf[f];
        float part = 0.f;
        if (lane < HID) {
            float acc = b1[lane];
            #pragma unroll
            for (int mm = 0; mm < NM; ++mm) acc = fmaf(feats[mm], W1[lane * NM + mm], acc);
            const float sg = 1.f / (1.f + __expf(-acc));
            part = acc * sg * W2[lane];
        }
        part += dppf<0xB1>(part);
        part += dppf<0x4E>(part);
        part += dppf<0x141>(part);
        part += dppf<0x128>(part);
        part = redfold16(part);
        part = redfold32(part);
        if (lane == 0) out[b] = part + b2[0];
    }
}

extern "C" void kernel_launch(void* const* d_in, const int* in_sizes, int n_in,
                              void* d_out, int out_size, void* d_ws, size_t ws_size,
                              hipStream_t stream) {
    (void)in_sizes; (void)n_in; (void)out_size; (void)d_ws; (void)ws_size;
    const float* theta = (const float*)d_in[0];
    const float* rotw  = (const float*)d_in[1];
    const float* esc   = (const float*)d_in[2];
    const float* ebi   = (const float*)d_in[3];
    const float* W1    = (const float*)d_in[4];
    const float* b1    = (const float*)d_in[5];
    const float* W2    = (const float*)d_in[6];
    const float* b2    = (const float*)d_in[7];
    float* out = (float*)d_out;

    qrh_kernel<<<BATCH, 128, 0, stream>>>(theta, rotw, esc, ebi, W1, b1, W2, b2, out);
}

// Round 11
// 104.068 us; speedup vs baseline: 1.0872x; 1.0872x over previous
//
#include <hip/hip_runtime.h>
#include <math.h>

#define NQ   10
#define NLAY 4
#define BATCH 4096
#define HID  32
#define NM   20   // 2*NQ

typedef float    f2  __attribute__((ext_vector_type(2)));
typedef unsigned u2v __attribute__((ext_vector_type(2)));

// ---------------------------------------------------------------------------
// Compile-time tracking of the CNOT ring as a GF(2) linear map.
// col[l][k] = pair-xor mask between storage indices for layer-l gate on wire k
// row[l][k] = parity mask giving logical bit x_k from storage index
// Storage bit layout: s = (lane<<4) | (r<<1) | wavebit
//   bits 9..4 -> lane (6b), bits 3..1 -> reg r (3b), bit 0 -> wave of pair
// ---------------------------------------------------------------------------
struct Tables {
    unsigned col[NLAY + 1][NQ];
    unsigned row[NLAY + 1][NQ];
};

constexpr Tables make_tables() {
    Tables t{};
    unsigned col[NQ] = {}, row[NQ] = {};
    for (int k = 0; k < NQ; ++k) { col[k] = 1u << (NQ - 1 - k); row[k] = 1u << (NQ - 1 - k); }
    for (int l = 0; l <= NLAY; ++l) {
        for (int k = 0; k < NQ; ++k) { t.col[l][k] = col[k]; t.row[l][k] = row[k]; }
        for (int k = 0; k < NQ; ++k) {            // ring: CNOT(k, (k+1)%NQ)
            int c = k, tg = (k + 1) % NQ;
            col[c] ^= col[tg];
            row[tg] ^= row[c];
        }
    }
    return t;
}

static constexpr Tables TB = make_tables();

struct cpx { float x, y; };
__device__ __forceinline__ cpx cxmul(cpx a, cpx b) {
    return { fmaf(a.x, b.x, -a.y * b.y), fmaf(a.x, b.y, a.y * b.x) };
}

__device__ __forceinline__ f2 mk2(float a, float b) { f2 r; r[0] = a; r[1] = b; return r; }
__device__ __forceinline__ f2 ffma(f2 a, f2 b, f2 c) { return __builtin_elementwise_fma(a, b, c); }

// acc += a (*) b   complex, interleaved (re,im) per f2 (VOP3P-foldable shapes).
__device__ __forceinline__ f2 cmac(f2 acc, f2 a, f2 b) {
    acc = ffma(mk2(a[0], a[0]), b, acc);
    acc = ffma(mk2(-a[1], a[1]), mk2(b[1], b[0]), acc);
    return acc;
}

// ---- DPP lane-xor within a 16-lane row (VALU pipe) ------------------------
template<int CTRL>
__device__ __forceinline__ float dppf(float x) {
    return __int_as_float(__builtin_amdgcn_update_dpp(
        0, __float_as_int(x), CTRL, 0xF, 0xF, true));
}

template<unsigned M>
__device__ __forceinline__ float dpplo(float x) {
    static_assert(M < 16u, "dpplo handles masks 0..15");
    if constexpr (M == 0u)       return x;
    else if constexpr (M == 1u)  return dppf<0xB1>(x);                 // quad_perm [1,0,3,2]
    else if constexpr (M == 2u)  return dppf<0x4E>(x);                 // quad_perm [2,3,0,1]
    else if constexpr (M == 3u)  return dppf<0x1B>(x);                 // quad_perm [3,2,1,0]
    else if constexpr (M == 7u)  return dppf<0x141>(x);                // row_half_mirror
    else if constexpr (M == 8u)  return dppf<0x128>(x);                // row_ror:8
    else if constexpr (M == 15u) return dppf<0x140>(x);                // row_mirror
    else if constexpr (M == 4u)  return dppf<0x141>(dppf<0x1B>(x));    // 7^3
    else if constexpr (M == 5u)  return dppf<0x141>(dppf<0x4E>(x));    // 7^2
    else if constexpr (M == 6u)  return dppf<0x141>(dppf<0xB1>(x));    // 7^1
    else if constexpr (M == 9u)  return dppf<0x128>(dppf<0xB1>(x));    // 8^1
    else if constexpr (M == 10u) return dppf<0x128>(dppf<0x4E>(x));    // 8^2
    else if constexpr (M == 11u) return dppf<0x128>(dppf<0x1B>(x));    // 8^3
    else if constexpr (M == 12u) return dppf<0x140>(dppf<0x1B>(x));    // 15^3
    else if constexpr (M == 13u) return dppf<0x140>(dppf<0x4E>(x));    // 15^2
    else                         return dppf<0x140>(dppf<0xB1>(x));    // 14 = 15^1
}

// Epilogue reduction folds: x + x^16 / x + x^32 (convention-independent)
__device__ __forceinline__ float redfold16(float x) {
#if __has_builtin(__builtin_amdgcn_permlane16_swap)
    u2v r = __builtin_amdgcn_permlane16_swap(__float_as_uint(x), __float_as_uint(x), false, false);
    return __uint_as_float(r[0]) + __uint_as_float(r[1]);
#else
    return x + __shfl_xor(x, 16);
#endif
}
__device__ __forceinline__ float redfold32(float x) {
#if __has_builtin(__builtin_amdgcn_permlane32_swap)
    u2v r = __builtin_amdgcn_permlane32_swap(__float_as_uint(x), __float_as_uint(x), false, false);
    return __uint_as_float(r[0]) + __uint_as_float(r[1]);
#else
    return x + __shfl_xor(x, 32);
#endif
}

// lane-xor by compile-time MASK — R8's proven pipe-balance policy:
// lane bits 4/5 -> DS pipe (ds_swizzle/bpermute), bits 0-3 -> DPP (VALU).
template<unsigned M>
__device__ __forceinline__ float xlane(float x) {
    if constexpr (M == 0u) return x;
    else if constexpr ((M & 48u) != 0u) return __shfl_xor(x, (int)M);   // DS pipe
    else return dpplo<M>(x);                                            // VALU pipe
}

#define XSTRIDE 18   // floats per lane slot in xbuf (72 B: 8-B aligned)

// ---- one single-qubit gate, 2-wave split state, fully specialized ---------
template<int L, int K>
__device__ __forceinline__ void apply_gate(f2 (&st)[8], const float4 (*gm)[2],
                                           float* xbuf, const int lane, const int wv) {
    constexpr unsigned v     = TB.col[L][K];
    constexpr unsigned m     = TB.row[L][K];
    constexpr unsigned vlane = (v >> 4) & 63u;
    constexpr int      vr    = (int)((v >> 1) & 7u);
    constexpr int      vw    = (int)(v & 1u);
    constexpr unsigned mlane = (m >> 4) & 63u;
    constexpr int      mr    = (int)((m >> 1) & 7u);
    constexpr int      mw    = (int)(m & 1u);
    constexpr int      gi    = L * NQ + K;

    int laneP = 0;
    if constexpr (mlane != 0u || mw != 0)
        laneP = (__popc((unsigned)lane & mlane) ^ (wv & mw)) & 1;
    const float4 A = gm[gi][laneP];
    const f2 ocA = mk2(A.x, A.y), pcA = mk2(A.z, A.w);
    f2 ocB = ocA, pcB = pcA;
    if constexpr (mr != 0) {
        const float4 B = gm[gi][laneP ^ 1];
        ocB = mk2(B.x, B.y); pcB = mk2(B.z, B.w);
    }

    f2 pv[8];
    if constexpr (vw != 0) {
        // cross-wave: exchange full half-state through LDS; the read address
        // absorbs the lane-xor and reg-xor parts of the pair mask.
        float* slot = xbuf + (unsigned)(wv * 64 + lane) * XSTRIDE;
        #pragma unroll
        for (int r = 0; r < 8; ++r) *(f2*)(slot + 2 * r) = st[r];
        __syncthreads();
        const float* ps = xbuf + (unsigned)((wv ^ 1) * 64 + (lane ^ (int)vlane)) * XSTRIDE;
        #pragma unroll
        for (int r = 0; r < 8; ++r) pv[r] = *(const f2*)(ps + 2 * (r ^ vr));
        __syncthreads();   // WAR: xbuf reused by the next exchange
    } else if constexpr (vlane != 0u) {
        #pragma unroll
        for (int r = 0; r < 8; ++r) {
            const f2 q = st[r ^ vr];
            pv[r] = mk2(xlane<vlane>(q[0]), xlane<vlane>(q[1]));
        }
    } else {
        #pragma unroll
        for (int r = 0; r < 8; ++r) pv[r] = st[r ^ vr];
    }

    #pragma unroll
    for (int r = 0; r < 8; ++r) {
        const int pr = __builtin_popcount((unsigned)(r & mr)) & 1;  // compile-time
        const f2 oc = pr ? ocB : ocA;
        const f2 pc = pr ? pcB : pcA;
        f2 acc = mk2(0.f, 0.f);
        acc = cmac(acc, oc, st[r]);
        acc = cmac(acc, pc, pv[r]);
        st[r] = acc;
    }
}

// One block = one batch element = 2 waves (128 threads); 8 amps (f2) per lane.
// No waves_per_eu clamp: natural VGPR (~56) still allows ~8 waves/SIMD.
__global__ __launch_bounds__(128)
void qrh_kernel(
    const float* __restrict__ theta, const float* __restrict__ rotw,
    const float* __restrict__ escale, const float* __restrict__ ebias,
    const float* __restrict__ W1, const float* __restrict__ b1,
    const float* __restrict__ W2, const float* __restrict__ b2,
    float* __restrict__ out)
{
    __shared__ float4 gmat[NLAY * NQ][2];   // [gate][U00,U01 | U11,U10]
    __shared__ float4 wtab[NQ];             // layer-0 product vectors
    __shared__ float  xbuf[2 * 64 * XSTRIDE];
    __shared__ float  fbuf[NM];

    const int tid  = threadIdx.x;
    const int lane = tid & 63;
    const int wv   = tid >> 6;     // wave of the pair = storage bit 0
    const int b    = blockIdx.x;

    // ---- per-gate 2x2 unitary, lane-parallel (threads 0..39) ----
    if (tid < NLAY * NQ) {
        const int g = tid, l = g / NQ, k = g % NQ;
        const float th = theta[b * NQ + k];
        const int e2 = (l * NQ + k) * 2;
        const float t0 = escale[e2 + 0] * th + ebias[e2 + 0];
        const float t1 = escale[e2 + 1] * th + ebias[e2 + 1];
        float sn0, c0, sn1, c1;
        __sincosf(0.5f * t0, &sn0, &c0);
        __sincosf(0.5f * t1, &sn1, &c1);
        // U_enc = RX(t1) RZ(t0)
        const f2 E00 = mk2( c1 * c0,  -c1 * sn0);
        const f2 E01 = mk2( sn1 * sn0, -sn1 * c0);
        const f2 E10 = mk2(-sn1 * sn0, -sn1 * c0);
        const f2 E11 = mk2( c1 * c0,   c1 * sn0);
        const int r3 = (l * NQ + k) * 3;
        const float w0 = rotw[r3 + 0], w1 = rotw[r3 + 1], w2 = rotw[r3 + 2];
        float cw, sw, ca0, sa0, ca1, sa1;
        __sincosf(0.5f * w1, &sw, &cw);
        __sincosf(0.5f * (w0 + w2), &sa0, &ca0);
        __sincosf(0.5f * (w0 - w2), &sa1, &ca1);
        // U_rot = RZ(w2) RY(w1) RZ(w0)
        const f2 R00 = mk2( cw * ca0, -cw * sa0);
        const f2 R01 = mk2(-sw * ca1, -sw * sa1);
        const f2 R10 = mk2( sw * ca1, -sw * sa1);
        const f2 R11 = mk2( cw * ca0,  cw * sa0);
        auto cm = [](f2 a, f2 bb) { return mk2(a[0]*bb[0] - a[1]*bb[1], a[0]*bb[1] + a[1]*bb[0]); };
        const f2 U00 = cm(R00, E00) + cm(R01, E10);
        const f2 U01 = cm(R00, E01) + cm(R01, E11);
        const f2 U10 = cm(R10, E00) + cm(R11, E10);
        const f2 U11 = cm(R10, E01) + cm(R11, E11);
        gmat[g][0] = make_float4(U00[0], U00[1], U01[0], U01[1]);
        gmat[g][1] = make_float4(U11[0], U11[1], U10[0], U10[1]);
        if (l == 0) {
            // layer-0 acts on |+>^10: per-wire 2-vector w = U*(1,1)/sqrt(2)
            const float inv = 0.70710678118654752f;
            const f2 al = (U00 + U01) * inv;
            const f2 be = (U10 + U11) * inv;
            wtab[k] = make_float4(al[0], al[1], be[0], be[1]);
        }
    }
    __syncthreads();

    // ---- layer-0 state = product state: amp(s) = prod_k w_k[s_k] ----------
    // s = (lane<<4)|(r<<1)|wv ; wires 0..5 <-> lane bits 5..0;
    // wires 6,7,8 <-> r bits 2..0; wire 9 <-> wv
    f2 st[8];
    {
        cpx pre;
        {
            const float4 q = wtab[0];
            pre = ((lane >> 5) & 1) ? cpx{q.z, q.w} : cpx{q.x, q.y};
            #pragma unroll
            for (int k = 1; k < 6; ++k) {
                const float4 t = wtab[k];
                const cpx w_ = ((lane >> (5 - k)) & 1) ? cpx{t.z, t.w} : cpx{t.x, t.y};
                pre = cxmul(pre, w_);
            }
            const float4 q9 = wtab[9];
            const cpx w9v = wv ? cpx{q9.z, q9.w} : cpx{q9.x, q9.y};
            pre = cxmul(pre, w9v);
        }
        const float4 q6 = wtab[6], q7 = wtab[7], q8 = wtab[8];
        const cpx w6[2] = {{q6.x, q6.y}, {q6.z, q6.w}};
        const cpx w7[2] = {{q7.x, q7.y}, {q7.z, q7.w}};
        const cpx w8[2] = {{q8.x, q8.y}, {q8.z, q8.w}};
        cpx ph[4];
        #pragma unroll
        for (int a = 0; a < 4; ++a) ph[a] = cxmul(cxmul(pre, w6[a >> 1]), w7[a & 1]);
        #pragma unroll
        for (int r = 0; r < 8; ++r) {
            const cpx t = cxmul(ph[r >> 1], w8[r & 1]);
            st[r] = mk2(t.x, t.y);
        }
    }

    const float4 (*gm)[2] = gmat;

    #define GATE(L,K) apply_gate<L,K>(st, gm, xbuf, lane, wv);
    #define LAYER(L) GATE(L,0) GATE(L,1) GATE(L,2) GATE(L,3) GATE(L,4) \
                     GATE(L,5) GATE(L,6) GATE(L,7) GATE(L,8) GATE(L,9)
    LAYER(1)
    LAYER(2)
    LAYER(3)
    #undef LAYER
    #undef GATE

    // ---- measurement: probs then 3-bit FWHT over register index ----
    float w[8];
    #pragma unroll
    for (int r = 0; r < 8; ++r) {
        const f2 sq = st[r] * st[r];
        w[r] = sq[0] + sq[1];
    }
    #pragma unroll
    for (int bit = 1; bit < 8; bit <<= 1) {
        #pragma unroll
        for (int j = 0; j < 8; ++j) {
            if (!(j & bit)) {
                const float a = w[j], c = w[j | bit];
                w[j] = a + c; w[j | bit] = a - c;
            }
        }
    }
    // w[t] = sum_r (-1)^{popc(r&t)} p[r]

    float feats[NM];
    #pragma unroll
    for (int f = 0; f < NM; ++f) {
        const unsigned M = (f < NQ) ? TB.row[NLAY][f]
                                    : (TB.row[NLAY][f - NQ] ^ TB.row[NLAY][(f - NQ + 1) % NQ]);
        const unsigned Mlane = (M >> 4) & 63u;
        const int Mr = (int)((M >> 1) & 7u);
        const int Mw = (int)(M & 1u);
        const float s = w[Mr];
        const int lsgn = (__popc((unsigned)lane & Mlane) ^ (wv & Mw)) & 1;
        feats[f] = lsgn ? -s : s;
    }
    // wave reduction over basis masks {1,2,7,8,16,32} (all VALU)
    #pragma unroll
    for (int f = 0; f < NM; ++f) {
        float v = feats[f];
        v += dppf<0xB1>(v);    // ^1
        v += dppf<0x4E>(v);    // ^2
        v += dppf<0x141>(v);   // ^7
        v += dppf<0x128>(v);   // ^8
        v = redfold16(v);
        v = redfold32(v);
        feats[f] = v;
    }

    // ---- cross-wave feat reduction + MLP head on wave 0 ----
    if (wv == 1 && lane == 0) {
        #pragma unroll
        for (int f = 0; f < NM; ++f) fbuf[f] = feats[f];
    }
    __syncthreads();
    if (wv == 0) {
        #pragma unroll
        for (int f = 0; f < NM; ++f) feats[f] += fbuf[f];
        float part = 0.f;
        if (lane < HID) {
            float acc = b1[lane];
            #pragma unroll
            for (int mm = 0; mm < NM; ++mm) acc = fmaf(feats[mm], W1[lane * NM + mm], acc);
            const float sg = 1.f / (1.f + __expf(-acc));
            part = acc * sg * W2[lane];
        }
        part += dppf<0xB1>(part);
        part += dppf<0x4E>(part);
        part += dppf<0x141>(part);
        part += dppf<0x128>(part);
        part = redfold16(part);
        part = redfold32(part);
        if (lane == 0) out[b] = part + b2[0];
    }
}

extern "C" void kernel_launch(void* const* d_in, const int* in_sizes, int n_in,
                              void* d_out, int out_size, void* d_ws, size_t ws_size,
                              hipStream_t stream) {
    (void)in_sizes; (void)n_in; (void)out_size; (void)d_ws; (void)ws_size;
    const float* theta = (const float*)d_in[0];
    const float* rotw  = (const float*)d_in[1];
    const float* esc   = (const float*)d_in[2];
    const float* ebi   = (const float*)d_in[3];
    const float* W1    = (const float*)d_in[4];
    const float* b1    = (const float*)d_in[5];
    const float* W2    = (const float*)d_in[6];
    const float* b2    = (const float*)d_in[7];
    float* out = (float*)d_out;

    qrh_kernel<<<BATCH, 128, 0, stream>>>(theta, rotw, esc, ebi, W1, b1, W2, b2, out);
}

// Round 12
// 95.413 us; speedup vs baseline: 1.1859x; 1.0907x over previous
//
#include <hip/hip_runtime.h>
#include <math.h>

#define NQ   10
#define NLAY 4
#define BATCH 4096
#define HID  32
#define NM   20   // 2*NQ

typedef float    f2  __attribute__((ext_vector_type(2)));
typedef unsigned u2v __attribute__((ext_vector_type(2)));

// ---------------------------------------------------------------------------
// Compile-time tracking of the CNOT ring as a GF(2) linear map.
// col[l][k] = pair-xor mask between storage indices for layer-l gate on wire k
// row[l][k] = parity mask giving logical bit x_k from storage index
// Storage bit layout THIS kernel: s = (halfLane << 5) | reg
//   bits 9..5 -> lane bits 4..0 (within a 32-lane half; wires 0..4)
//   bits 4..0 -> reg index r in 0..31 (wires 5..9)
// Lane bit 5 selects the batch element (two elements per wave) — no mask
// ever touches it, so the halves are automatically isolated.
// ---------------------------------------------------------------------------
struct Tables {
    unsigned col[NLAY + 1][NQ];
    unsigned row[NLAY + 1][NQ];
};

constexpr Tables make_tables() {
    Tables t{};
    unsigned col[NQ] = {}, row[NQ] = {};
    for (int k = 0; k < NQ; ++k) { col[k] = 1u << (NQ - 1 - k); row[k] = 1u << (NQ - 1 - k); }
    for (int l = 0; l <= NLAY; ++l) {
        for (int k = 0; k < NQ; ++k) { t.col[l][k] = col[k]; t.row[l][k] = row[k]; }
        for (int k = 0; k < NQ; ++k) {            // ring: CNOT(k, (k+1)%NQ)
            int c = k, tg = (k + 1) % NQ;
            col[c] ^= col[tg];
            row[tg] ^= row[c];
        }
    }
    return t;
}

static constexpr Tables TB = make_tables();

struct cpx { float x, y; };
__device__ __forceinline__ cpx cxmul(cpx a, cpx b) {
    return { fmaf(a.x, b.x, -a.y * b.y), fmaf(a.x, b.y, a.y * b.x) };
}

__device__ __forceinline__ f2 mk2(float a, float b) { f2 r; r[0] = a; r[1] = b; return r; }
__device__ __forceinline__ f2 ffma(f2 a, f2 b, f2 c) { return __builtin_elementwise_fma(a, b, c); }

// acc += a (*) b   complex, interleaved (re,im) per f2 (VOP3P-foldable shapes).
__device__ __forceinline__ f2 cmac(f2 acc, f2 a, f2 b) {
    acc = ffma(mk2(a[0], a[0]), b, acc);
    acc = ffma(mk2(-a[1], a[1]), mk2(b[1], b[0]), acc);
    return acc;
}

// ---- DPP lane-xor within a 16-lane row (VALU pipe) ------------------------
template<int CTRL>
__device__ __forceinline__ float dppf(float x) {
    return __int_as_float(__builtin_amdgcn_update_dpp(
        0, __float_as_int(x), CTRL, 0xF, 0xF, true));
}

template<unsigned M>
__device__ __forceinline__ float dpplo(float x) {
    static_assert(M < 16u, "dpplo handles masks 0..15");
    if constexpr (M == 0u)       return x;
    else if constexpr (M == 1u)  return dppf<0xB1>(x);                 // quad_perm [1,0,3,2]
    else if constexpr (M == 2u)  return dppf<0x4E>(x);                 // quad_perm [2,3,0,1]
    else if constexpr (M == 3u)  return dppf<0x1B>(x);                 // quad_perm [3,2,1,0]
    else if constexpr (M == 7u)  return dppf<0x141>(x);                // row_half_mirror
    else if constexpr (M == 8u)  return dppf<0x128>(x);                // row_ror:8
    else if constexpr (M == 15u) return dppf<0x140>(x);                // row_mirror
    else if constexpr (M == 4u)  return dppf<0x141>(dppf<0x1B>(x));    // 7^3
    else if constexpr (M == 5u)  return dppf<0x141>(dppf<0x4E>(x));    // 7^2
    else if constexpr (M == 6u)  return dppf<0x141>(dppf<0xB1>(x));    // 7^1
    else if constexpr (M == 9u)  return dppf<0x128>(dppf<0xB1>(x));    // 8^1
    else if constexpr (M == 10u) return dppf<0x128>(dppf<0x4E>(x));    // 8^2
    else if constexpr (M == 11u) return dppf<0x128>(dppf<0x1B>(x));    // 8^3
    else if constexpr (M == 12u) return dppf<0x140>(dppf<0x1B>(x));    // 15^3
    else if constexpr (M == 13u) return dppf<0x140>(dppf<0x4E>(x));    // 15^2
    else                         return dppf<0x140>(dppf<0xB1>(x));    // 14 = 15^1
}

// x + x^16 fold (convention-independent permlane16_swap; within a 32-half)
__device__ __forceinline__ float redfold16(float x) {
#if __has_builtin(__builtin_amdgcn_permlane16_swap)
    u2v r = __builtin_amdgcn_permlane16_swap(__float_as_uint(x), __float_as_uint(x), false, false);
    return __uint_as_float(r[0]) + __uint_as_float(r[1]);
#else
    return x + __shfl_xor(x, 16);
#endif
}

// lane-xor by compile-time MASK (MASK <= 31, never crosses the half):
// bit 4 present -> DS pipe (single shfl_xor); bits 0..3 only -> DPP (VALU).
template<unsigned M>
__device__ __forceinline__ float xlane(float x) {
    if constexpr (M == 0u) return x;
    else if constexpr ((M & 16u) != 0u) return __shfl_xor(x, (int)M);   // DS pipe
    else return dpplo<M>(x);                                            // VALU pipe
}

// ---- one single-qubit gate, 32 amps/lane, fully specialized ---------------
// gm points at this element's 40-gate table slice.
template<int L, int K>
__device__ __forceinline__ void apply_gate(f2 (&st)[32], const float4 (*gm)[2],
                                           const int lane) {
    constexpr unsigned v     = TB.col[L][K];
    constexpr unsigned m     = TB.row[L][K];
    constexpr unsigned vlane = (v >> 5) & 31u;
    constexpr int      vr    = (int)(v & 31u);
    constexpr unsigned mlane = (m >> 5) & 31u;
    constexpr int      mr    = (int)(m & 31u);
    constexpr int      gi    = L * NQ + K;

    int laneP = 0;
    if constexpr (mlane != 0u) laneP = __popc((unsigned)lane & mlane) & 1;
    const float4 A = gm[gi][laneP];
    const f2 ocA = mk2(A.x, A.y), pcA = mk2(A.z, A.w);
    f2 ocB = ocA, pcB = pcA;
    if constexpr (mr != 0) {
        const float4 B = gm[gi][laneP ^ 1];
        ocB = mk2(B.x, B.y); pcB = mk2(B.z, B.w);
    }

    // pair-local processing keeps liveness minimal (st 64 regs + ~8 temps)
    #pragma unroll
    for (int r = 0; r < 32; ++r) {
        const int r2 = r ^ vr;
        if (r2 < r) continue;
        f2 p_r, p_r2;
        if constexpr (vlane != 0u) {
            p_r = mk2(xlane<vlane>(st[r2][0]), xlane<vlane>(st[r2][1]));
            if (r2 != r)
                p_r2 = mk2(xlane<vlane>(st[r][0]), xlane<vlane>(st[r][1]));
        } else {
            p_r = st[r2];
            p_r2 = st[r];
        }
        {
            const int pr = __builtin_popcount((unsigned)(r & mr)) & 1;
            const f2 oc = pr ? ocB : ocA;
            const f2 pc = pr ? pcB : pcA;
            f2 acc = mk2(0.f, 0.f);
            acc = cmac(acc, oc, st[r]);
            acc = cmac(acc, pc, p_r);
            if (r2 != r) {
                const int pr2 = __builtin_popcount((unsigned)(r2 & mr)) & 1;
                const f2 oc2 = pr2 ? ocB : ocA;
                const f2 pc2 = pr2 ? pcB : pcA;
                f2 acc2 = mk2(0.f, 0.f);
                acc2 = cmac(acc2, oc2, st[r2]);
                acc2 = cmac(acc2, pc2, p_r2);
                st[r2] = acc2;
            }
            st[r] = acc;
        }
    }
}

// One block = 256 threads = 4 waves = 8 batch elements (2 per wave, one per
// 32-lane half). No barriers in the gate loop; grid = BATCH/8 = 512 blocks.
__global__ __launch_bounds__(256, 2)
void qrh_kernel(
    const float* __restrict__ theta, const float* __restrict__ rotw,
    const float* __restrict__ escale, const float* __restrict__ ebias,
    const float* __restrict__ W1, const float* __restrict__ b1,
    const float* __restrict__ W2, const float* __restrict__ b2,
    float* __restrict__ out)
{
    // per element, per gate: group0=[U00,U01], group1=[U11,U10]
    __shared__ float4 gmat[8 * NLAY * NQ][2];
    __shared__ float4 wtab[8][NQ];   // layer-0 product vectors per element

    const int tid  = threadIdx.x;
    const int lane = tid & 63;
    const int wv   = tid >> 6;
    const int e    = (tid & 255) >> 5 >= 0 ? ((wv << 1) | (lane >> 5)) : 0;  // element in block 0..7
    const int b    = blockIdx.x * 8 + e;

    // ---- per-gate 2x2 unitary, thread-parallel over 8*40 = 320 gates ----
    for (int g = tid; g < 8 * NLAY * NQ; g += 256) {
        const int ge = g / (NLAY * NQ);       // element 0..7
        const int gg = g % (NLAY * NQ);
        const int l = gg / NQ, k = gg % NQ;
        const int gb = blockIdx.x * 8 + ge;
        const float th = theta[gb * NQ + k];
        const int e2 = (l * NQ + k) * 2;
        const float t0 = escale[e2 + 0] * th + ebias[e2 + 0];
        const float t1 = escale[e2 + 1] * th + ebias[e2 + 1];
        float sn0, c0, sn1, c1;
        __sincosf(0.5f * t0, &sn0, &c0);
        __sincosf(0.5f * t1, &sn1, &c1);
        // U_enc = RX(t1) RZ(t0)
        const f2 E00 = mk2( c1 * c0,  -c1 * sn0);
        const f2 E01 = mk2( sn1 * sn0, -sn1 * c0);
        const f2 E10 = mk2(-sn1 * sn0, -sn1 * c0);
        const f2 E11 = mk2( c1 * c0,   c1 * sn0);
        const int r3 = (l * NQ + k) * 3;
        const float w0 = rotw[r3 + 0], w1 = rotw[r3 + 1], w2 = rotw[r3 + 2];
        float cw, sw, ca0, sa0, ca1, sa1;
        __sincosf(0.5f * w1, &sw, &cw);
        __sincosf(0.5f * (w0 + w2), &sa0, &ca0);
        __sincosf(0.5f * (w0 - w2), &sa1, &ca1);
        // U_rot = RZ(w2) RY(w1) RZ(w0)
        const f2 R00 = mk2( cw * ca0, -cw * sa0);
        const f2 R01 = mk2(-sw * ca1, -sw * sa1);
        const f2 R10 = mk2( sw * ca1, -sw * sa1);
        const f2 R11 = mk2( cw * ca0,  cw * sa0);
        auto cm = [](f2 a, f2 bb) { return mk2(a[0]*bb[0] - a[1]*bb[1], a[0]*bb[1] + a[1]*bb[0]); };
        const f2 U00 = cm(R00, E00) + cm(R01, E10);
        const f2 U01 = cm(R00, E01) + cm(R01, E11);
        const f2 U10 = cm(R10, E00) + cm(R11, E10);
        const f2 U11 = cm(R10, E01) + cm(R11, E11);
        gmat[g][0] = make_float4(U00[0], U00[1], U01[0], U01[1]);
        gmat[g][1] = make_float4(U11[0], U11[1], U10[0], U10[1]);
        if (l == 0) {
            // layer-0 acts on |+>^10: per-wire 2-vector w = U*(1,1)/sqrt(2)
            const float inv = 0.70710678118654752f;
            const f2 al = (U00 + U01) * inv;
            const f2 be = (U10 + U11) * inv;
            wtab[ge][k] = make_float4(al[0], al[1], be[0], be[1]);
        }
    }
    __syncthreads();

    // ---- layer-0 state = product state: amp(s) = prod_k w_k[s_k] ----------
    // s = (halfLane<<5) | r ; wires 0..4 <-> halfLane bits 4..0;
    // wires 5..9 <-> r bits 4..0
    const int hl = lane & 31;
    f2 st[32];
    {
        cpx pre;
        {
            const float4 q = wtab[e][0];
            pre = ((hl >> 4) & 1) ? cpx{q.z, q.w} : cpx{q.x, q.y};
            #pragma unroll
            for (int k = 1; k < 5; ++k) {
                const float4 t = wtab[e][k];
                const cpx w_ = ((hl >> (4 - k)) & 1) ? cpx{t.z, t.w} : cpx{t.x, t.y};
                pre = cxmul(pre, w_);
            }
        }
        const float4 q5 = wtab[e][5], q6 = wtab[e][6], q7 = wtab[e][7];
        const float4 q8 = wtab[e][8], q9 = wtab[e][9];
        const cpx w5[2] = {{q5.x, q5.y}, {q5.z, q5.w}};
        const cpx w6[2] = {{q6.x, q6.y}, {q6.z, q6.w}};
        const cpx w7[2] = {{q7.x, q7.y}, {q7.z, q7.w}};
        const cpx w8[2] = {{q8.x, q8.y}, {q8.z, q8.w}};
        const cpx w9[2] = {{q9.x, q9.y}, {q9.z, q9.w}};
        cpx a7[8];
        #pragma unroll
        for (int j = 0; j < 8; ++j)
            a7[j] = cxmul(cxmul(cxmul(pre, w5[j >> 2]), w6[(j >> 1) & 1]), w7[j & 1]);
        #pragma unroll
        for (int r = 0; r < 32; ++r) {
            const cpx t = cxmul(cxmul(a7[r >> 2], w8[(r >> 1) & 1]), w9[r & 1]);
            st[r] = mk2(t.x, t.y);
        }
    }

    const float4 (*gm)[2] = &gmat[e * NLAY * NQ];

    #define GATE(L,K) apply_gate<L,K>(st, gm, lane);
    #define LAYER(L) GATE(L,0) GATE(L,1) GATE(L,2) GATE(L,3) GATE(L,4) \
                     GATE(L,5) GATE(L,6) GATE(L,7) GATE(L,8) GATE(L,9)
    LAYER(1)
    LAYER(2)
    LAYER(3)
    #undef LAYER
    #undef GATE

    // ---- measurement: probs then 5-bit FWHT over register index ----
    float w[32];
    #pragma unroll
    for (int r = 0; r < 32; ++r) {
        const f2 sq = st[r] * st[r];
        w[r] = sq[0] + sq[1];
    }
    #pragma unroll
    for (int bit = 1; bit < 32; bit <<= 1) {
        #pragma unroll
        for (int j = 0; j < 32; ++j) {
            if (!(j & bit)) {
                const float a = w[j], c = w[j | bit];
                w[j] = a + c; w[j | bit] = a - c;
            }
        }
    }
    // w[t] = sum_r (-1)^{popc(r&t)} p[r]

    float feats[NM];
    #pragma unroll
    for (int f = 0; f < NM; ++f) {
        const unsigned M = (f < NQ) ? TB.row[NLAY][f]
                                    : (TB.row[NLAY][f - NQ] ^ TB.row[NLAY][(f - NQ + 1) % NQ]);
        const unsigned Mlane = (M >> 5) & 31u;
        const int Mr = (int)(M & 31u);
        const float s = w[Mr];
        const int lsgn = __popc((unsigned)lane & Mlane) & 1;
        feats[f] = lsgn ? -s : s;
    }
    // reduction within the 32-lane half over basis masks {1,2,7,8,16}
    #pragma unroll
    for (int f = 0; f < NM; ++f) {
        float v = feats[f];
        v += dppf<0xB1>(v);    // ^1
        v += dppf<0x4E>(v);    // ^2
        v += dppf<0x141>(v);   // ^7
        v += dppf<0x128>(v);   // ^8
        v = redfold16(v);      // ^16
        feats[f] = v;
    }

    // ---- MLP head: each lane of the half computes one hidden unit ----
    float part;
    {
        float acc = b1[hl];
        #pragma unroll
        for (int mm = 0; mm < NM; ++mm) acc = fmaf(feats[mm], W1[hl * NM + mm], acc);
        const float sg = 1.f / (1.f + __expf(-acc));
        part = acc * sg * W2[hl];
    }
    part += dppf<0xB1>(part);
    part += dppf<0x4E>(part);
    part += dppf<0x141>(part);
    part += dppf<0x128>(part);
    part = redfold16(part);
    if (hl == 0) out[b] = part + b2[0];
}

extern "C" void kernel_launch(void* const* d_in, const int* in_sizes, int n_in,
                              void* d_out, int out_size, void* d_ws, size_t ws_size,
                              hipStream_t stream) {
    (void)in_sizes; (void)n_in; (void)out_size; (void)d_ws; (void)ws_size;
    const float* theta = (const float*)d_in[0];
    const float* rotw  = (const float*)d_in[1];
    const float* esc   = (const float*)d_in[2];
    const float* ebi   = (const float*)d_in[3];
    const float* W1    = (const float*)d_in[4];
    const float* b1    = (const float*)d_in[5];
    const float* W2    = (const float*)d_in[6];
    const float* b2    = (const float*)d_in[7];
    float* out = (float*)d_out;

    qrh_kernel<<<BATCH / 8, 256, 0, stream>>>(theta, rotw, esc, ebi, W1, b1, W2, b2, out);
}

// Round 13
// 92.105 us; speedup vs baseline: 1.2285x; 1.0359x over previous
//
#include <hip/hip_runtime.h>
#include <math.h>

#define NQ   10
#define NLAY 4
#define BATCH 4096
#define HID  32
#define NM   20   // 2*NQ

typedef float    f2  __attribute__((ext_vector_type(2)));
typedef unsigned u2v __attribute__((ext_vector_type(2)));

// ---------------------------------------------------------------------------
// Compile-time tracking of the CNOT ring as a GF(2) linear map.
// col[l][k] = pair-xor mask between storage indices for layer-l gate on wire k
// row[l][k] = parity mask giving logical bit x_k from storage index
// Storage bit layout: s = (halfLane << 5) | reg
//   bits 9..5 -> lane bits 4..0 (within a 32-lane half; wires 0..4)
//   bits 4..0 -> reg index r in 0..31 (wires 5..9)
// Lane bit 5 selects the batch element (two elements per wave); no mask
// touches it, and ds_swizzle is 32-lane granular, so halves stay isolated.
// ---------------------------------------------------------------------------
struct Tables {
    unsigned col[NLAY + 1][NQ];
    unsigned row[NLAY + 1][NQ];
};

constexpr Tables make_tables() {
    Tables t{};
    unsigned col[NQ] = {}, row[NQ] = {};
    for (int k = 0; k < NQ; ++k) { col[k] = 1u << (NQ - 1 - k); row[k] = 1u << (NQ - 1 - k); }
    for (int l = 0; l <= NLAY; ++l) {
        for (int k = 0; k < NQ; ++k) { t.col[l][k] = col[k]; t.row[l][k] = row[k]; }
        for (int k = 0; k < NQ; ++k) {            // ring: CNOT(k, (k+1)%NQ)
            int c = k, tg = (k + 1) % NQ;
            col[c] ^= col[tg];
            row[tg] ^= row[c];
        }
    }
    return t;
}

static constexpr Tables TB = make_tables();

struct cpx { float x, y; };
__device__ __forceinline__ cpx cxmul(cpx a, cpx b) {
    return { fmaf(a.x, b.x, -a.y * b.y), fmaf(a.x, b.y, a.y * b.x) };
}

__device__ __forceinline__ f2 mk2(float a, float b) { f2 r; r[0] = a; r[1] = b; return r; }
__device__ __forceinline__ f2 ffma(f2 a, f2 b, f2 c) { return __builtin_elementwise_fma(a, b, c); }

// acc += a (*) b   complex, interleaved (re,im) per f2 (VOP3P-foldable shapes).
__device__ __forceinline__ f2 cmac(f2 acc, f2 a, f2 b) {
    acc = ffma(mk2(a[0], a[0]), b, acc);
    acc = ffma(mk2(-a[1], a[1]), mk2(b[1], b[0]), acc);
    return acc;
}

// ---- DPP lane-xor within a 16-lane row (VALU pipe) ------------------------
template<int CTRL>
__device__ __forceinline__ float dppf(float x) {
    return __int_as_float(__builtin_amdgcn_update_dpp(
        0, __float_as_int(x), CTRL, 0xF, 0xF, true));
}

template<unsigned M>
__device__ __forceinline__ float dpplo(float x) {
    static_assert(M < 16u, "dpplo handles masks 0..15");
    if constexpr (M == 0u)       return x;
    else if constexpr (M == 1u)  return dppf<0xB1>(x);                 // quad_perm [1,0,3,2]
    else if constexpr (M == 2u)  return dppf<0x4E>(x);                 // quad_perm [2,3,0,1]
    else if constexpr (M == 3u)  return dppf<0x1B>(x);                 // quad_perm [3,2,1,0]
    else if constexpr (M == 7u)  return dppf<0x141>(x);                // row_half_mirror
    else if constexpr (M == 8u)  return dppf<0x128>(x);                // row_ror:8
    else if constexpr (M == 15u) return dppf<0x140>(x);                // row_mirror
    else if constexpr (M == 4u)  return dppf<0x141>(dppf<0x1B>(x));    // 7^3
    else if constexpr (M == 5u)  return dppf<0x141>(dppf<0x4E>(x));    // 7^2
    else if constexpr (M == 6u)  return dppf<0x141>(dppf<0xB1>(x));    // 7^1
    else if constexpr (M == 9u)  return dppf<0x128>(dppf<0xB1>(x));    // 8^1
    else if constexpr (M == 10u) return dppf<0x128>(dppf<0x4E>(x));    // 8^2
    else if constexpr (M == 11u) return dppf<0x128>(dppf<0x1B>(x));    // 8^3
    else if constexpr (M == 12u) return dppf<0x140>(dppf<0x1B>(x));    // 15^3
    else if constexpr (M == 13u) return dppf<0x140>(dppf<0x4E>(x));    // 15^2
    else                         return dppf<0x140>(dppf<0xB1>(x));    // 14 = 15^1
}

// x + x^16 fold (convention-independent permlane16_swap; within a 32-half)
__device__ __forceinline__ float redfold16(float x) {
#if __has_builtin(__builtin_amdgcn_permlane16_swap)
    u2v r = __builtin_amdgcn_permlane16_swap(__float_as_uint(x), __float_as_uint(x), false, false);
    return __uint_as_float(r[0]) + __uint_as_float(r[1]);
#else
    return x + __shfl_xor(x, 16);
#endif
}

// lane-xor by compile-time MASK (MASK <= 31, never crosses the half):
// bit 4 present -> ONE ds_swizzle (BitMode, compile-time offset, zero VALU);
// bits 0..3 only -> DPP on the VALU pipe.
template<unsigned M>
__device__ __forceinline__ float xlane(float x) {
    if constexpr (M == 0u) return x;
    else if constexpr ((M & 16u) != 0u)
        return __int_as_float(__builtin_amdgcn_ds_swizzle(
            __float_as_int(x), (int)((M << 10) | 0x1F)));   // xor within 32 lanes
    else return dpplo<M>(x);                                // VALU pipe
}

// ---- one single-qubit gate, 32 amps/lane, fully specialized ---------------
template<int L, int K>
__device__ __forceinline__ void apply_gate(f2 (&st)[32], const float4 (*gm)[2],
                                           const int lane) {
    constexpr unsigned v     = TB.col[L][K];
    constexpr unsigned m     = TB.row[L][K];
    constexpr unsigned vlane = (v >> 5) & 31u;
    constexpr int      vr    = (int)(v & 31u);
    constexpr unsigned mlane = (m >> 5) & 31u;
    constexpr int      mr    = (int)(m & 31u);
    constexpr int      gi    = L * NQ + K;

    int laneP = 0;
    if constexpr (mlane != 0u) laneP = __popc((unsigned)lane & mlane) & 1;
    const float4 A = gm[gi][laneP];
    const f2 ocA = mk2(A.x, A.y), pcA = mk2(A.z, A.w);
    f2 ocB = ocA, pcB = pcA;
    if constexpr (mr != 0) {
        const float4 B = gm[gi][laneP ^ 1];
        ocB = mk2(B.x, B.y); pcB = mk2(B.z, B.w);
    }

    // pair-local processing keeps liveness minimal
    #pragma unroll
    for (int r = 0; r < 32; ++r) {
        const int r2 = r ^ vr;
        if (r2 < r) continue;
        f2 p_r, p_r2;
        if constexpr (vlane != 0u) {
            p_r = mk2(xlane<vlane>(st[r2][0]), xlane<vlane>(st[r2][1]));
            if (r2 != r)
                p_r2 = mk2(xlane<vlane>(st[r][0]), xlane<vlane>(st[r][1]));
        } else {
            p_r = st[r2];
            p_r2 = st[r];
        }
        {
            const int pr = __builtin_popcount((unsigned)(r & mr)) & 1;
            const f2 oc = pr ? ocB : ocA;
            const f2 pc = pr ? pcB : pcA;
            f2 acc = mk2(0.f, 0.f);
            acc = cmac(acc, oc, st[r]);
            acc = cmac(acc, pc, p_r);
            if (r2 != r) {
                const int pr2 = __builtin_popcount((unsigned)(r2 & mr)) & 1;
                const f2 oc2 = pr2 ? ocB : ocA;
                const f2 pc2 = pr2 ? pcB : pcA;
                f2 acc2 = mk2(0.f, 0.f);
                acc2 = cmac(acc2, oc2, st[r2]);
                acc2 = cmac(acc2, pc2, p_r2);
                st[r2] = acc2;
            }
            st[r] = acc;
        }
    }
}

// One block = 256 threads = 4 waves = 8 batch elements (2 per wave, one per
// 32-lane half). No barriers in the gate loop; grid = BATCH/8 = 512 blocks.
__global__ __launch_bounds__(256, 2)
void qrh_kernel(
    const float* __restrict__ theta, const float* __restrict__ rotw,
    const float* __restrict__ escale, const float* __restrict__ ebias,
    const float* __restrict__ W1, const float* __restrict__ b1,
    const float* __restrict__ W2, const float* __restrict__ b2,
    float* __restrict__ out)
{
    // per element, per gate: group0=[U00,U01], group1=[U11,U10]
    __shared__ float4 gmat[8 * NLAY * NQ][2];
    __shared__ float4 wtab[8][NQ];   // layer-0 product vectors per element

    const int tid  = threadIdx.x;
    const int lane = tid & 63;
    const int wv   = tid >> 6;
    const int e    = (wv << 1) | (lane >> 5);   // element in block 0..7
    const int b    = blockIdx.x * 8 + e;

    // ---- per-gate 2x2 unitary, thread-parallel over 8*40 = 320 gates ----
    for (int g = tid; g < 8 * NLAY * NQ; g += 256) {
        const int ge = g / (NLAY * NQ);       // element 0..7
        const int gg = g % (NLAY * NQ);
        const int l = gg / NQ, k = gg % NQ;
        const int gb = blockIdx.x * 8 + ge;
        const float th = theta[gb * NQ + k];
        const int e2 = (l * NQ + k) * 2;
        const float t0 = escale[e2 + 0] * th + ebias[e2 + 0];
        const float t1 = escale[e2 + 1] * th + ebias[e2 + 1];
        float sn0, c0, sn1, c1;
        __sincosf(0.5f * t0, &sn0, &c0);
        __sincosf(0.5f * t1, &sn1, &c1);
        // U_enc = RX(t1) RZ(t0)
        const f2 E00 = mk2( c1 * c0,  -c1 * sn0);
        const f2 E01 = mk2( sn1 * sn0, -sn1 * c0);
        const f2 E10 = mk2(-sn1 * sn0, -sn1 * c0);
        const f2 E11 = mk2( c1 * c0,   c1 * sn0);
        const int r3 = (l * NQ + k) * 3;
        const float w0 = rotw[r3 + 0], w1 = rotw[r3 + 1], w2 = rotw[r3 + 2];
        float cw, sw, ca0, sa0, ca1, sa1;
        __sincosf(0.5f * w1, &sw, &cw);
        __sincosf(0.5f * (w0 + w2), &sa0, &ca0);
        __sincosf(0.5f * (w0 - w2), &sa1, &ca1);
        // U_rot = RZ(w2) RY(w1) RZ(w0)
        const f2 R00 = mk2( cw * ca0, -cw * sa0);
        const f2 R01 = mk2(-sw * ca1, -sw * sa1);
        const f2 R10 = mk2( sw * ca1, -sw * sa1);
        const f2 R11 = mk2( cw * ca0,  cw * sa0);
        auto cm = [](f2 a, f2 bb) { return mk2(a[0]*bb[0] - a[1]*bb[1], a[0]*bb[1] + a[1]*bb[0]); };
        const f2 U00 = cm(R00, E00) + cm(R01, E10);
        const f2 U01 = cm(R00, E01) + cm(R01, E11);
        const f2 U10 = cm(R10, E00) + cm(R11, E10);
        const f2 U11 = cm(R10, E01) + cm(R11, E11);
        gmat[g][0] = make_float4(U00[0], U00[1], U01[0], U01[1]);
        gmat[g][1] = make_float4(U11[0], U11[1], U10[0], U10[1]);
        if (l == 0) {
            // layer-0 acts on |+>^10: per-wire 2-vector w = U*(1,1)/sqrt(2)
            const float inv = 0.70710678118654752f;
            const f2 al = (U00 + U01) * inv;
            const f2 be = (U10 + U11) * inv;
            wtab[ge][k] = make_float4(al[0], al[1], be[0], be[1]);
        }
    }
    __syncthreads();

    // ---- de-synchronize DS bursts: odd waves start the gate pipeline late.
    if (wv & 1) { __builtin_amdgcn_s_sleep(10); __builtin_amdgcn_s_sleep(10); }

    // ---- layer-0 state = product state: amp(s) = prod_k w_k[s_k] ----------
    const int hl = lane & 31;
    f2 st[32];
    {
        cpx pre;
        {
            const float4 q = wtab[e][0];
            pre = ((hl >> 4) & 1) ? cpx{q.z, q.w} : cpx{q.x, q.y};
            #pragma unroll
            for (int k = 1; k < 5; ++k) {
                const float4 t = wtab[e][k];
                const cpx w_ = ((hl >> (4 - k)) & 1) ? cpx{t.z, t.w} : cpx{t.x, t.y};
                pre = cxmul(pre, w_);
            }
        }
        const float4 q5 = wtab[e][5], q6 = wtab[e][6], q7 = wtab[e][7];
        const float4 q8 = wtab[e][8], q9 = wtab[e][9];
        const cpx w5[2] = {{q5.x, q5.y}, {q5.z, q5.w}};
        const cpx w6[2] = {{q6.x, q6.y}, {q6.z, q6.w}};
        const cpx w7[2] = {{q7.x, q7.y}, {q7.z, q7.w}};
        const cpx w8[2] = {{q8.x, q8.y}, {q8.z, q8.w}};
        const cpx w9[2] = {{q9.x, q9.y}, {q9.z, q9.w}};
        cpx a7[8];
        #pragma unroll
        for (int j = 0; j < 8; ++j)
            a7[j] = cxmul(cxmul(cxmul(pre, w5[j >> 2]), w6[(j >> 1) & 1]), w7[j & 1]);
        #pragma unroll
        for (int r = 0; r < 32; ++r) {
            const cpx t = cxmul(cxmul(a7[r >> 2], w8[(r >> 1) & 1]), w9[r & 1]);
            st[r] = mk2(t.x, t.y);
        }
    }

    const float4 (*gm)[2] = &gmat[e * NLAY * NQ];

    #define GATE(L,K) apply_gate<L,K>(st, gm, lane);
    #define LAYER(L) GATE(L,0) GATE(L,1) GATE(L,2) GATE(L,3) GATE(L,4) \
                     GATE(L,5) GATE(L,6) GATE(L,7) GATE(L,8) GATE(L,9)
    LAYER(1)
    LAYER(2)
    LAYER(3)
    #undef LAYER
    #undef GATE

    // ---- measurement: probs then 5-bit FWHT over register index ----
    float w[32];
    #pragma unroll
    for (int r = 0; r < 32; ++r) {
        const f2 sq = st[r] * st[r];
        w[r] = sq[0] + sq[1];
    }
    #pragma unroll
    for (int bit = 1; bit < 32; bit <<= 1) {
        #pragma unroll
        for (int j = 0; j < 32; ++j) {
            if (!(j & bit)) {
                const float a = w[j], c = w[j | bit];
                w[j] = a + c; w[j | bit] = a - c;
            }
        }
    }
    // w[t] = sum_r (-1)^{popc(r&t)} p[r]

    float feats[NM];
    #pragma unroll
    for (int f = 0; f < NM; ++f) {
        const unsigned M = (f < NQ) ? TB.row[NLAY][f]
                                    : (TB.row[NLAY][f - NQ] ^ TB.row[NLAY][(f - NQ + 1) % NQ]);
        const unsigned Mlane = (M >> 5) & 31u;
        const int Mr = (int)(M & 31u);
        const float s = w[Mr];
        const int lsgn = __popc((unsigned)lane & Mlane) & 1;
        feats[f] = lsgn ? -s : s;
    }
    // reduction within the 32-lane half over basis masks {1,2,7,8,16}
    #pragma unroll
    for (int f = 0; f < NM; ++f) {
        float v = feats[f];
        v += dppf<0xB1>(v);    // ^1
        v += dppf<0x4E>(v);    // ^2
        v += dppf<0x141>(v);   // ^7
        v += dppf<0x128>(v);   // ^8
        v = redfold16(v);      // ^16
        feats[f] = v;
    }

    // ---- MLP head: each lane of the half computes one hidden unit ----
    float part;
    {
        float acc = b1[hl];
        #pragma unroll
        for (int mm = 0; mm < NM; ++mm) acc = fmaf(feats[mm], W1[hl * NM + mm], acc);
        const float sg = 1.f / (1.f + __expf(-acc));
        part = acc * sg * W2[hl];
    }
    part += dppf<0xB1>(part);
    part += dppf<0x4E>(part);
    part += dppf<0x141>(part);
    part += dppf<0x128>(part);
    part = redfold16(part);
    if (hl == 0) out[b] = part + b2[0];
}

extern "C" void kernel_launch(void* const* d_in, const int* in_sizes, int n_in,
                              void* d_out, int out_size, void* d_ws, size_t ws_size,
                              hipStream_t stream) {
    (void)in_sizes; (void)n_in; (void)out_size; (void)d_ws; (void)ws_size;
    const float* theta = (const float*)d_in[0];
    const float* rotw  = (const float*)d_in[1];
    const float* esc   = (const float*)d_in[2];
    const float* ebi   = (const float*)d_in[3];
    const float* W1    = (const float*)d_in[4];
    const float* b1    = (const float*)d_in[5];
    const float* W2    = (const float*)d_in[6];
    const float* b2    = (const float*)d_in[7];
    float* out = (float*)d_out;

    qrh_kernel<<<BATCH / 8, 256, 0, stream>>>(theta, rotw, esc, ebi, W1, b1, W2, b2, out);
}